// Round 4
// baseline (17.997 us; speedup 1.0000x reference)
//
#include <hip/hip_runtime.h>
#include <math.h>

#define IMGS 28
#define NPSD 14
#define NPAT 196
#define NCLS 10
#define NFEAT (NPAT * 3)

// Native trig: args in [-pi/2, pi/2]; ~1e-6 err vs 1e-2 threshold.
__device__ __forceinline__ void fsincos(float x, float& s, float& c) {
    s = __sinf(x);
    c = __cosf(x);
}

// Each thread holds 8 amplitudes: global state i = (k<<1)|e, e = lane&1 (qubit3).
// Local masks on k: q0=4, q1=2, q2=1.

template <int MASK>
__device__ __forceinline__ void ry8r(float (&hr)[8], float c, float s) {  // real phase
#pragma unroll
    for (int k = 0; k < 8; ++k) {
        if (k & MASK) continue;
        const int j = k | MASK;
        float r0 = hr[k], r1 = hr[j];
        hr[k] = c * r0 - s * r1;
        hr[j] = s * r0 + c * r1;
    }
}

template <int MASK>
__device__ __forceinline__ void ry8(float (&hr)[8], float (&hi)[8], float c, float s) {
#pragma unroll
    for (int k = 0; k < 8; ++k) {
        if (k & MASK) continue;
        const int j = k | MASK;
        float r0 = hr[k], q0 = hi[k], r1 = hr[j], q1 = hi[j];
        hr[k] = c * r0 - s * r1;  hi[k] = c * q0 - s * q1;
        hr[j] = s * r0 + c * r1;  hi[j] = s * q0 + c * q1;
    }
}

template <int MC, int MT>
__device__ __forceinline__ void cx8r(float (&hr)[8]) {
#pragma unroll
    for (int k = 0; k < 8; ++k)
        if ((k & MC) && !(k & MT)) {
            const int j = k | MT;
            float t = hr[k]; hr[k] = hr[j]; hr[j] = t;
        }
}

template <int MC, int MT>
__device__ __forceinline__ void cx8(float (&hr)[8], float (&hi)[8]) {
#pragma unroll
    for (int k = 0; k < 8; ++k)
        if ((k & MC) && !(k & MT)) {
            const int j = k | MT;
            float t = hr[k]; hr[k] = hr[j]; hr[j] = t;
            t = hi[k]; hi[k] = hi[j]; hi[j] = t;
        }
}

template <int MC, int MT>
__device__ __forceinline__ void crx8(float (&hr)[8], float (&hi)[8], float c, float s) {
#pragma unroll
    for (int k = 0; k < 8; ++k) {
        if ((k & MC) && !(k & MT)) {
            const int j = k | MT;
            float r0 = hr[k], q0 = hi[k], r1 = hr[j], q1 = hi[j];
            hr[k] = c * r0 + s * q1;  hi[k] = c * q0 - s * r1;
            hr[j] = c * r1 + s * q0;  hi[j] = c * q1 - s * r0;
        }
    }
}

__global__ __launch_bounds__(512) void qcnn_split_kernel(
        const float* __restrict__ x, const float* __restrict__ qw,
        const float* __restrict__ fc_w, const float* __restrict__ fc_b,
        float* __restrict__ out) {
    __shared__ float partial[8][NCLS];

    const int b = blockIdx.x;
    const int t = threadIdx.x;
    const int p = t >> 1;   // patch index
    const int e = t & 1;    // this lane's qubit-3 value

    float con[NCLS];
#pragma unroll
    for (int c = 0; c < NCLS; ++c) con[c] = 0.0f;

    if (p < NPAT) {
        // ---- patch pixels (two float2 rows) ----
        const int pr = p / NPSD, pc = p % NPSD;
        const float* img = x + (size_t)b * (IMGS * IMGS);
        const float2 rw0 = *(const float2*)(img + (2 * pr) * IMGS + 2 * pc);
        const float2 rw1 = *(const float2*)(img + (2 * pr + 1) * IMGS + 2 * pc);

        const float HPI = 1.57079632679489662f;  // pi/2
        float c0, s0, c1, s1, c2, s2, c3, s3;
        fsincos(rw0.x * HPI, s0, c0);
        fsincos(rw0.y * HPI, s1, c1);
        fsincos(rw1.x * HPI, s2, c2);
        fsincos(rw1.y * HPI, s3, c3);
        const float t3 = e ? s3 : c3;

        float hr[8], hi[8];
#pragma unroll
        for (int k = 0; k < 8; ++k) {
            hr[k] = ((k & 4) ? s0 : c0) * ((k & 2) ? s1 : c1) * ((k & 1) ? s2 : c2) * t3;
            hi[k] = 0.0f;
        }

        float cw[12], sw[12];
#pragma unroll
        for (int i = 0; i < 12; ++i) fsincos(qw[i] * 0.5f, sw[i], cw[i]);

        // ---- conv1 (state real throughout) ----
        ry8r<4>(hr, cw[0], sw[0]);          // RY q0
        ry8r<2>(hr, cw[1], sw[1]);          // RY q1
        cx8r<4, 2>(hr);                     // CX q0->q1
        ry8r<1>(hr, cw[2], sw[2]);          // RY q2
        // RY q3: cross-lane pair (e=0,e=1)
        {
            const float ssel = e ? sw[3] : -sw[3];
#pragma unroll
            for (int k = 0; k < 8; ++k) {
                float pv = __shfl_xor(hr[k], 1, 64);
                hr[k] = cw[3] * hr[k] + ssel * pv;
            }
        }
        // CX q2->q3: states with q2=1 (k odd) swap across lanes
#pragma unroll
        for (int k = 1; k < 8; k += 2) hr[k] = __shfl_xor(hr[k], 1, 64);
        cx8r<2, 1>(hr);                     // CX q1->q2
        // CX q3->q0: e=1 lanes swap k <-> k^4
        {
            float old[8];
#pragma unroll
            for (int k = 0; k < 8; ++k) old[k] = hr[k];
#pragma unroll
            for (int k = 0; k < 8; ++k) hr[k] = e ? old[k ^ 4] : old[k];
        }

        // ---- pool1 ----
        crx8<2, 4>(hr, hi, cw[4], sw[4]);   // CRX c=q1 t=q0 (hi=0 folds; introduces imag)
        // CRX c=q3 t=q2: e-predicated RX on q2 (identity on e=0 via cc=1,ss=0)
        {
            const float cc = e ? cw[5] : 1.0f;
            const float ss = e ? sw[5] : 0.0f;
#pragma unroll
            for (int k = 0; k < 8; k += 2) {
                const int j = k | 1;
                float ra = hr[k], qa = hi[k], rb = hr[j], qb = hi[j];
                hr[k] = cc * ra + ss * qb;  hi[k] = cc * qa - ss * rb;
                hr[j] = cc * rb + ss * qa;  hi[j] = cc * qb - ss * ra;
            }
        }

        // ---- conv2 ----
        ry8<4>(hr, hi, cw[6], sw[6]);       // RY q0
        ry8<1>(hr, hi, cw[7], sw[7]);       // RY q2
        cx8<4, 1>(hr, hi);                  // CX q0->q2
        ry8<4>(hr, hi, cw[8], sw[8]);       // RY q0
        ry8<1>(hr, hi, cw[9], sw[9]);       // RY q2

        // ---- pool2 ----
        crx8<1, 4>(hr, hi, cw[10], sw[10]); // CRX c=q2 t=q0
        ry8<4>(hr, hi, cw[11], sw[11]);     // RY q0

        // ---- Bloch partials for this lane's q3 slice ----
        float ex = 0.f, ey = 0.f, ez = 0.f;
#pragma unroll
        for (int k = 0; k < 4; ++k) {
            const int j = k | 4;
            float r0 = hr[k], q0 = hi[k], r1 = hr[j], q1 = hi[j];
            ex += r0 * r1 + q0 * q1;
            ey += r0 * q1 - q0 * r1;
            ez += (r0 * r0 + q0 * q0) - (r1 * r1 + q1 * q1);
        }
        ex *= 2.0f;
        ey *= 2.0f;

        // ---- per-class contribution (both lanes of a pair hold partials) ----
#pragma unroll
        for (int c = 0; c < NCLS; ++c) {
            const float* w = fc_w + c * NFEAT + 3 * p;
            con[c] = ex * w[0] + ey * w[1] + ez * w[2];
        }
    }

    // ---- 64-lane butterfly: sums both pair-halves and 32 patches per wave ----
#pragma unroll
    for (int c = 0; c < NCLS; ++c) {
        float v = con[c];
#pragma unroll
        for (int off = 32; off >= 1; off >>= 1) v += __shfl_xor(v, off, 64);
        con[c] = v;
    }

    const int wave = t >> 6, lane = t & 63;
    if (lane == 0) {
#pragma unroll
        for (int c = 0; c < NCLS; ++c) partial[wave][c] = con[c];
    }
    __syncthreads();

    if (t < NCLS) {
        float acc = fc_b[t];
#pragma unroll
        for (int w = 0; w < 8; ++w) acc += partial[w][t];
        out[b * NCLS + t] = acc;
    }
}

extern "C" void kernel_launch(void* const* d_in, const int* in_sizes, int n_in,
                              void* d_out, int out_size, void* d_ws, size_t ws_size,
                              hipStream_t stream) {
    const float* x    = (const float*)d_in[0];
    const float* qw   = (const float*)d_in[1];
    const float* fc_w = (const float*)d_in[2];
    const float* fc_b = (const float*)d_in[3];
    float* out = (float*)d_out;

    const int B = in_sizes[0] / (IMGS * IMGS);
    qcnn_split_kernel<<<B, 512, 0, stream>>>(x, qw, fc_w, fc_b, out);
}

// Round 6
// 10.251 us; speedup vs baseline: 1.7557x; 1.7557x over previous
//
#include <hip/hip_runtime.h>
#include <math.h>

#define IMGS 28
#define NPSD 14
#define NPAT 196
#define NCLS 10
#define NFEAT (NPAT * 3)

// Native trig: args all in [-pi/2, pi/2]; ~1e-6 err vs 1e-2 threshold.
__device__ __forceinline__ void fsincos(float x, float& s, float& c) {
    s = __sinf(x);
    c = __cosf(x);
}

// ---- 4-qubit gate helpers: all indices compile-time (templates + unroll) ----

template <int MASK>
__device__ __forceinline__ void ry_gate(float (&sr)[16], float (&si)[16], float c, float s) {
#pragma unroll
    for (int i = 0; i < 16; ++i) {
        if (i & MASK) continue;
        const int j = i | MASK;
        float r0 = sr[i], q0 = si[i], r1 = sr[j], q1 = si[j];
        sr[i] = c * r0 - s * r1;  si[i] = c * q0 - s * q1;
        sr[j] = s * r0 + c * r1;  si[j] = s * q0 + c * q1;
    }
}

template <int MC, int MT>
__device__ __forceinline__ void cx_gate(float (&sr)[16], float (&si)[16]) {
#pragma unroll
    for (int i = 0; i < 16; ++i) {
        if ((i & MC) && !(i & MT)) {
            const int j = i | MT;
            float tr = sr[i], ti = si[i];
            sr[i] = sr[j]; si[i] = si[j];
            sr[j] = tr;    si[j] = ti;
        }
    }
}

template <int MC, int MT>
__device__ __forceinline__ void crx_gate(float (&sr)[16], float (&si)[16], float c, float s) {
#pragma unroll
    for (int i = 0; i < 16; ++i) {
        if ((i & MC) && !(i & MT)) {
            const int j = i | MT;
            float r0 = sr[i], q0 = si[i], r1 = sr[j], q1 = si[j];
            sr[i] = c * r0 + s * q1;  si[i] = c * q0 - s * r1;
            sr[j] = c * r1 + s * q0;  si[j] = c * q1 - s * r0;
        }
    }
}

__global__ __launch_bounds__(256) void qcnn_fused_kernel(
        const float* __restrict__ x, const float* __restrict__ qw,
        const float* __restrict__ fc_w, const float* __restrict__ fc_b,
        float* __restrict__ out) {
    __shared__ float partial[4][NCLS];

    const int b = blockIdx.x;
    const int t = threadIdx.x;

    float con[NCLS];
#pragma unroll
    for (int c = 0; c < NCLS; ++c) con[c] = 0.0f;

    if (t < NPAT) {
        // ---- issue ALL global loads first: pixels + fc_w rows. Their
        // latency hides under the ~2000-cycle trig+circuit chain below. ----
        const int pr = t / NPSD, pc = t % NPSD;
        const float* img = x + (size_t)b * (IMGS * IMGS);
        const float2 rw0 = *(const float2*)(img + (2 * pr) * IMGS + 2 * pc);
        const float2 rw1 = *(const float2*)(img + (2 * pr + 1) * IMGS + 2 * pc);

        float w0[NCLS], w1[NCLS], w2[NCLS];
#pragma unroll
        for (int c = 0; c < NCLS; ++c) {
            const float* w = fc_w + c * NFEAT + 3 * t;
            w0[c] = w[0]; w1[c] = w[1]; w2[c] = w[2];
        }

        // ---- data encoding: product state of RY(a*pi) on |0> per qubit ----
        float ce[4], se[4];
        const float HPI = 1.57079632679489662f;  // pi/2 (half of angle a*pi)
        fsincos(rw0.x * HPI, se[0], ce[0]);
        fsincos(rw0.y * HPI, se[1], ce[1]);
        fsincos(rw1.x * HPI, se[2], ce[2]);
        fsincos(rw1.y * HPI, se[3], ce[3]);

        float sr[16], si[16];
#pragma unroll
        for (int i = 0; i < 16; ++i) {
            float v = ((i & 8) ? se[0] : ce[0]) * ((i & 4) ? se[1] : ce[1]) *
                      ((i & 2) ? se[2] : ce[2]) * ((i & 1) ? se[3] : ce[3]);
            sr[i] = v;
            si[i] = 0.0f;   // compiler constant-folds imag through conv1
        }

        // ---- circuit weights (broadcast loads, cached) ----
        float cw[12], sw[12];
#pragma unroll
        for (int i = 0; i < 12; ++i) fsincos(qw[i] * 0.5f, sw[i], cw[i]);

        // qubit q <-> mask (8 >> q)
        // conv1
        ry_gate<8>(sr, si, cw[0], sw[0]);
        ry_gate<4>(sr, si, cw[1], sw[1]);
        cx_gate<8, 4>(sr, si);
        ry_gate<2>(sr, si, cw[2], sw[2]);
        ry_gate<1>(sr, si, cw[3], sw[3]);
        cx_gate<2, 1>(sr, si);
        cx_gate<4, 2>(sr, si);
        cx_gate<1, 8>(sr, si);
        // pool1
        crx_gate<4, 8>(sr, si, cw[4], sw[4]);
        crx_gate<1, 2>(sr, si, cw[5], sw[5]);
        // conv2
        ry_gate<8>(sr, si, cw[6], sw[6]);
        ry_gate<2>(sr, si, cw[7], sw[7]);
        cx_gate<8, 2>(sr, si);
        ry_gate<8>(sr, si, cw[8], sw[8]);
        ry_gate<2>(sr, si, cw[9], sw[9]);
        // pool2
        crx_gate<2, 8>(sr, si, cw[10], sw[10]);
        ry_gate<8>(sr, si, cw[11], sw[11]);

        // ---- Bloch vector of qubit 0 ----
        float ex = 0.f, ey = 0.f, ez = 0.f;
#pragma unroll
        for (int j = 0; j < 8; ++j) {
            float r0 = sr[j], q0 = si[j], r1 = sr[j + 8], q1 = si[j + 8];
            ex += r0 * r1 + q0 * q1;
            ey += r0 * q1 - q0 * r1;
            ez += (r0 * r0 + q0 * q0) - (r1 * r1 + q1 * q1);
        }
        ex *= 2.0f;
        ey *= 2.0f;

        // ---- fold features into per-class contributions (regs preloaded) ----
#pragma unroll
        for (int c = 0; c < NCLS; ++c)
            con[c] = ex * w0[c] + ey * w1[c] + ez * w2[c];
    }

    // ---- 64-lane butterfly reduce per class (known-good round-3 path) ----
#pragma unroll
    for (int c = 0; c < NCLS; ++c) {
        float v = con[c];
#pragma unroll
        for (int off = 32; off >= 1; off >>= 1) v += __shfl_xor(v, off, 64);
        con[c] = v;
    }

    const int wave = t >> 6, lane = t & 63;
    if (lane == 0) {
#pragma unroll
        for (int c = 0; c < NCLS; ++c) partial[wave][c] = con[c];
    }
    __syncthreads();

    if (t < NCLS) {
        out[b * NCLS + t] = partial[0][t] + partial[1][t] + partial[2][t] +
                            partial[3][t] + fc_b[t];
    }
}

extern "C" void kernel_launch(void* const* d_in, const int* in_sizes, int n_in,
                              void* d_out, int out_size, void* d_ws, size_t ws_size,
                              hipStream_t stream) {
    const float* x    = (const float*)d_in[0];
    const float* qw   = (const float*)d_in[1];
    const float* fc_w = (const float*)d_in[2];
    const float* fc_b = (const float*)d_in[3];
    float* out = (float*)d_out;

    const int B = in_sizes[0] / (IMGS * IMGS);
    qcnn_fused_kernel<<<B, 256, 0, stream>>>(x, qw, fc_w, fc_b, out);
}

// Round 7
// 10.230 us; speedup vs baseline: 1.7594x; 1.0021x over previous
//
#include <hip/hip_runtime.h>
#include <math.h>

#define IMGS 28
#define NPSD 14
#define NPAT 196
#define NCLS 10
#define NFEAT (NPAT * 3)

// Native trig: args all in [-pi, pi]; ~1e-6 err vs 1e-2 threshold.
__device__ __forceinline__ void fsincos(float x, float& s, float& c) {
    s = __sinf(x);
    c = __cosf(x);
}

// ---- 4-qubit gate helpers: all indices compile-time (templates + unroll) ----

template <int MASK>
__device__ __forceinline__ void ry_gate(float (&sr)[16], float (&si)[16], float c, float s) {
#pragma unroll
    for (int i = 0; i < 16; ++i) {
        if (i & MASK) continue;
        const int j = i | MASK;
        float r0 = sr[i], q0 = si[i], r1 = sr[j], q1 = si[j];
        sr[i] = c * r0 - s * r1;  si[i] = c * q0 - s * q1;
        sr[j] = s * r0 + c * r1;  si[j] = s * q0 + c * q1;
    }
}

template <int MC, int MT>
__device__ __forceinline__ void cx_gate(float (&sr)[16], float (&si)[16]) {
#pragma unroll
    for (int i = 0; i < 16; ++i) {
        if ((i & MC) && !(i & MT)) {
            const int j = i | MT;
            float tr = sr[i], ti = si[i];
            sr[i] = sr[j]; si[i] = si[j];
            sr[j] = tr;    si[j] = ti;
        }
    }
}

template <int MC, int MT>
__device__ __forceinline__ void crx_gate(float (&sr)[16], float (&si)[16], float c, float s) {
#pragma unroll
    for (int i = 0; i < 16; ++i) {
        if ((i & MC) && !(i & MT)) {
            const int j = i | MT;
            float r0 = sr[i], q0 = si[i], r1 = sr[j], q1 = si[j];
            sr[i] = c * r0 + s * q1;  si[i] = c * q0 - s * r1;
            sr[j] = c * r1 + s * q0;  si[j] = c * q1 - s * r0;
        }
    }
}

__global__ __launch_bounds__(256) void qcnn_fused_kernel(
        const float* __restrict__ x, const float* __restrict__ qw,
        const float* __restrict__ fc_w, const float* __restrict__ fc_b,
        float* __restrict__ out) {
    __shared__ float partial[4][NCLS];

    const int b = blockIdx.x;
    const int t = threadIdx.x;

    float con[NCLS];
#pragma unroll
    for (int c = 0; c < NCLS; ++c) con[c] = 0.0f;

    if (t < NPAT) {
        // ---- issue all global loads first (latency hides under circuit) ----
        const int pr = t / NPSD, pc = t % NPSD;
        const float* img = x + (size_t)b * (IMGS * IMGS);
        const float2 rw0 = *(const float2*)(img + (2 * pr) * IMGS + 2 * pc);
        const float2 rw1 = *(const float2*)(img + (2 * pr + 1) * IMGS + 2 * pc);

        float w0[NCLS], w1[NCLS], w2[NCLS];
#pragma unroll
        for (int c = 0; c < NCLS; ++c) {
            const float* w = fc_w + c * NFEAT + 3 * t;
            w0[c] = w[0]; w1[c] = w[1]; w2[c] = w[2];
        }

        // ---- data encoding: product state of RY(a*pi) on |0> per qubit ----
        float ce[4], se[4];
        const float HPI = 1.57079632679489662f;  // pi/2 (half of angle a*pi)
        fsincos(rw0.x * HPI, se[0], ce[0]);
        fsincos(rw0.y * HPI, se[1], ce[1]);
        fsincos(rw1.x * HPI, se[2], ce[2]);
        fsincos(rw1.y * HPI, se[3], ce[3]);

        float sr[16], si[16];
#pragma unroll
        for (int i = 0; i < 16; ++i) {
            float v = ((i & 8) ? se[0] : ce[0]) * ((i & 4) ? se[1] : ce[1]) *
                      ((i & 2) ? se[2] : ce[2]) * ((i & 1) ? se[3] : ce[3]);
            sr[i] = v;
            si[i] = 0.0f;   // constant-folds imag through conv1
        }

        // ---- circuit weights: half-angle for gates 0..9; FULL angle for the
        // absorbed gates 10,11 (observable rotation uses cos/sin of theta) ----
        float cw[10], sw[10];
#pragma unroll
        for (int i = 0; i < 10; ++i) fsincos(qw[i] * 0.5f, sw[i], cw[i]);
        float c10, s10, c11, s11;
        fsincos(qw[10], s10, c10);
        fsincos(qw[11], s11, c11);

        // qubit q <-> mask (8 >> q)
        // conv1
        ry_gate<8>(sr, si, cw[0], sw[0]);
        ry_gate<4>(sr, si, cw[1], sw[1]);
        cx_gate<8, 4>(sr, si);
        ry_gate<2>(sr, si, cw[2], sw[2]);
        ry_gate<1>(sr, si, cw[3], sw[3]);
        cx_gate<2, 1>(sr, si);
        cx_gate<4, 2>(sr, si);
        cx_gate<1, 8>(sr, si);
        // pool1
        crx_gate<4, 8>(sr, si, cw[4], sw[4]);
        crx_gate<1, 2>(sr, si, cw[5], sw[5]);
        // conv2
        ry_gate<8>(sr, si, cw[6], sw[6]);
        ry_gate<2>(sr, si, cw[7], sw[7]);
        cx_gate<8, 2>(sr, si);
        ry_gate<8>(sr, si, cw[8], sw[8]);
        ry_gate<2>(sr, si, cw[9], sw[9]);
        // pool2: CRX(q2->q0, qw10) and RY(q0, qw11) are ABSORBED into the
        // observables below (Heisenberg picture) — not applied to the state.

        // ---- Bloch partials of qubit 0, split by q2 (mask 2) ----
        float x0 = 0.f, y0 = 0.f, z0 = 0.f;   // q2 = 0 amplitudes
        float x1 = 0.f, y1 = 0.f, z1 = 0.f;   // q2 = 1 amplitudes
#pragma unroll
        for (int j = 0; j < 8; ++j) {
            float r0 = sr[j], q0 = si[j], r1 = sr[j + 8], q1 = si[j + 8];
            float xx = r0 * r1 + q0 * q1;
            float yy = r0 * q1 - q0 * r1;
            float zz = (r0 * r0 + q0 * q0) - (r1 * r1 + q1 * q1);
            if (j & 2) { x1 += xx; y1 += yy; z1 += zz; }
            else       { x0 += xx; y0 += yy; z0 += zz; }
        }
        // True Bloch components: X_b = 2*x_b, Y_b = 2*y_b, Z_b = z_b.
        // P' = RY(w11)^dag P RY(w11):  X->c11*X+s11*Z, Y->Y, Z->c11*Z-s11*X
        // CRX(q2->q0,w10)^dag on q2=1 block:  Y->c10*Y-s10*Z, Z->c10*Z+s10*Y
        const float U = 2.0f * (x0 + x1);                      // <X> pre-rotation
        const float T = z0 + c10 * z1 + 2.0f * s10 * y1;       // <Z''>
        const float fx = c11 * U + s11 * T;
        const float fy = 2.0f * y0 + 2.0f * c10 * y1 - s10 * z1;
        const float fz = c11 * T - s11 * U;

        // ---- fold features into per-class contributions (regs preloaded) ----
#pragma unroll
        for (int c = 0; c < NCLS; ++c)
            con[c] = fx * w0[c] + fy * w1[c] + fz * w2[c];
    }

    // ---- 64-lane butterfly reduce per class (known-good path) ----
#pragma unroll
    for (int c = 0; c < NCLS; ++c) {
        float v = con[c];
#pragma unroll
        for (int off = 32; off >= 1; off >>= 1) v += __shfl_xor(v, off, 64);
        con[c] = v;
    }

    const int wave = t >> 6, lane = t & 63;
    if (lane == 0) {
#pragma unroll
        for (int c = 0; c < NCLS; ++c) partial[wave][c] = con[c];
    }
    __syncthreads();

    if (t < NCLS) {
        out[b * NCLS + t] = partial[0][t] + partial[1][t] + partial[2][t] +
                            partial[3][t] + fc_b[t];
    }
}

extern "C" void kernel_launch(void* const* d_in, const int* in_sizes, int n_in,
                              void* d_out, int out_size, void* d_ws, size_t ws_size,
                              hipStream_t stream) {
    const float* x    = (const float*)d_in[0];
    const float* qw   = (const float*)d_in[1];
    const float* fc_w = (const float*)d_in[2];
    const float* fc_b = (const float*)d_in[3];
    float* out = (float*)d_out;

    const int B = in_sizes[0] / (IMGS * IMGS);
    qcnn_fused_kernel<<<B, 256, 0, stream>>>(x, qw, fc_w, fc_b, out);
}